// Round 23
// baseline (82.681 us; speedup 1.0000x reference)
//
#include <hip/hip_runtime.h>
#include <hip/hip_bf16.h>
#include <math.h>

#define BB 64
#define SS 400
#define F2H 512
#define HID 256
#define EMB 128
#define NGATE 1024
#define VOC 50000
#define CH 64
#define NCHK 7
#define NKC 16
#define KSP 12

typedef short bf16x8 __attribute__((ext_vector_type(8)));
typedef float f32x4 __attribute__((ext_vector_type(4)));

__device__ __forceinline__ float sigm(float x) { return 1.0f / (1.0f + __expf(-x)); }

__device__ __forceinline__ float ftanh(float x) {
    float e = __expf(2.0f * x);
    return 1.0f - 2.0f / (e + 1.0f);
}

__device__ __forceinline__ ushort f2bf(float x) {
    uint32_t u = __float_as_uint(x);
    uint32_t r = u + 0x7FFFu + ((u >> 16) & 1u);
    return (ushort)(r >> 16);
}

__device__ __forceinline__ float bf2f(ushort u) {
    return __uint_as_float(((uint32_t)u) << 16);
}

__device__ __forceinline__ bf16x8 cvt8(float4 a, float4 b) {
    __hip_bfloat162 p0 = __float22bfloat162_rn({a.x, a.y});
    __hip_bfloat162 p1 = __float22bfloat162_rn({a.z, a.w});
    __hip_bfloat162 p2 = __float22bfloat162_rn({b.x, b.y});
    __hip_bfloat162 p3 = __float22bfloat162_rn({b.z, b.w});
    union { bf16x8 v; uint32_t u[4]; } r;
    r.u[0] = *(uint32_t*)&p0;
    r.u[1] = *(uint32_t*)&p1;
    r.u[2] = *(uint32_t*)&p2;
    r.u[3] = *(uint32_t*)&p3;
    return r.v;
}

// ---------------- K1a: gates partial GEMM (12-way k-split) + wenc pack ----------------
__global__ __launch_bounds__(256) void k_gates(
    const int* __restrict__ word, const float* __restrict__ hidden,
    const float* __restrict__ embed, const float* __restrict__ W_ih,
    const float* __restrict__ W_hh, float* __restrict__ part,
    const float* __restrict__ attn_W, ushort* __restrict__ wenc_pk)
{
    const int gt = blockIdx.x;
    const int ks = blockIdx.y;
    const int tid = threadIdx.x;

    if (ks == KSP) {
#pragma unroll
        for (int r = 0; r < 4; ++r) {
            int u = gt * 1024 + r * 256 + tid;
            int l = u & 63;
            int t = (u >> 6) & 15;
            int nt = u >> 10;
            int n = nt * 16 + (l & 15);
            int k0 = t * 32 + (l >> 4) * 8;
            const float4* src = (const float4*)&attn_W[n * 768 + k0];
            float4 f0 = src[0], f1 = src[1];
            *(bf16x8*)&wenc_pk[(size_t)u * 8] = cvt8(f0, f1);
        }
        return;
    }

    __shared__ float As[32 * 68];
    __shared__ float Bs[32 * 68];
    const int g0 = gt * 64;
    const int kc = ks * 32;
    float acc[4][4];
#pragma unroll
    for (int i = 0; i < 4; ++i)
#pragma unroll
        for (int j = 0; j < 4; ++j) acc[i][j] = 0.0f;

    const int tb = tid >> 4;
    const int tg = tid & 15;
    const int srow = tid >> 3;
    const int skk = (tid & 7) * 4;

#pragma unroll
    for (int p = 0; p < 2; ++p) {
        int rr = srow + p * 32;
        int gk = kc + skk;
        float4 f;
        if (gk < EMB) {
            int w = word[rr];
            f = *(const float4*)&embed[w * EMB + gk];
        } else {
            f = *(const float4*)&hidden[rr * HID + gk - EMB];
        }
        As[(skk + 0) * 68 + rr] = f.x;
        As[(skk + 1) * 68 + rr] = f.y;
        As[(skk + 2) * 68 + rr] = f.z;
        As[(skk + 3) * 68 + rr] = f.w;
    }
#pragma unroll
    for (int p = 0; p < 2; ++p) {
        int nn = srow + p * 32;
        int g = g0 + nn;
        int gk = kc + skk;
        float4 f;
        if (gk < EMB) f = *(const float4*)&W_ih[g * EMB + gk];
        else          f = *(const float4*)&W_hh[g * HID + gk - EMB];
        Bs[(skk + 0) * 68 + nn] = f.x;
        Bs[(skk + 1) * 68 + nn] = f.y;
        Bs[(skk + 2) * 68 + nn] = f.z;
        Bs[(skk + 3) * 68 + nn] = f.w;
    }
    __syncthreads();
#pragma unroll 8
    for (int k = 0; k < 32; ++k) {
        float4 a = *(const float4*)&As[k * 68 + tb * 4];
        float4 b = *(const float4*)&Bs[k * 68 + tg * 4];
        float av[4] = {a.x, a.y, a.z, a.w};
        float bv[4] = {b.x, b.y, b.z, b.w};
#pragma unroll
        for (int i = 0; i < 4; ++i)
#pragma unroll
            for (int j = 0; j < 4; ++j) acc[i][j] += av[i] * bv[j];
    }
    float* dst = part + ks * (BB * NGATE);
#pragma unroll
    for (int i = 0; i < 4; ++i) {
        int b = tb * 4 + i;
        float4 o = {acc[i][0], acc[i][1], acc[i][2], acc[i][3]};
        *(float4*)&dst[b * NGATE + g0 + tg * 4] = o;
    }
}

// ---------------- K1b: LSTM pointwise + hproj (4-way col-split) ----------------
__global__ __launch_bounds__(256) void k_lstm(
    const float* __restrict__ part, const float* __restrict__ cell,
    const float* __restrict__ b_ih, const float* __restrict__ b_hh,
    const float* __restrict__ attn_W, const float* __restrict__ attn_b,
    float* __restrict__ h_out, float* __restrict__ c_out, float* __restrict__ hproj)
{
    const int b = blockIdx.x;
    const int qg = blockIdx.y;
    const int u = threadIdx.x;
    __shared__ float hrow[HID];

    float gi = b_ih[u] + b_hh[u];
    float gf = b_ih[u + 256] + b_hh[u + 256];
    float gg = b_ih[u + 512] + b_hh[u + 512];
    float go = b_ih[u + 768] + b_hh[u + 768];
#pragma unroll
    for (int ks = 0; ks < KSP; ++ks) {
        const float* p = part + ks * (BB * NGATE) + b * NGATE;
        gi += p[u];
        gf += p[u + 256];
        gg += p[u + 512];
        go += p[u + 768];
    }
    float c = sigm(gf) * cell[b * HID + u] + sigm(gi) * tanhf(gg);
    float h = tanhf(sigm(go) * tanhf(c));
    if (qg == 0) {
        c_out[b * HID + u] = c;
        h_out[b * HID + u] = h;
    }
    hrow[u] = h;
    __syncthreads();

    const int col = qg * 64 + (u >> 2);
    const int kq = u & 3;
    const float* wr = attn_W + col * 768 + 512 + kq * 64;
    const float* hr = hrow + kq * 64;
    float acc = 0.f;
#pragma unroll 8
    for (int k = 0; k < 64; k += 4) {
        float4 wv = *(const float4*)&wr[k];
        acc += hr[k] * wv.x + hr[k + 1] * wv.y + hr[k + 2] * wv.z + hr[k + 3] * wv.w;
    }
    acc += __shfl_xor(acc, 1);
    acc += __shfl_xor(acc, 2);
    if (kq == 0) hproj[b * HID + col] = acc + attn_b[col];
}

// ---------------- K2: fused attention ----------------
__global__ __launch_bounds__(512, 4) void k_attn(
    const float* __restrict__ enc, const ushort* __restrict__ wenc_pk,
    const float* __restrict__ hproj, const float* __restrict__ vvec,
    float* __restrict__ ctxp, float* __restrict__ mls)
{
    const int b   = blockIdx.x / NCHK;
    const int chk = blockIdx.x % NCHK;
    const int s0  = chk * CH;
    const int tid = threadIdx.x;
    const int l = tid & 63;
    const int w = tid >> 6;
    const int wr = w >> 2, wc = w & 3;
    const int brow0 = b * SS;
    const int ln = l & 15, q = l >> 4;

    __shared__ ushort Asm[CH * 512];
    __shared__ float ps[CH];
    __shared__ float pool[7 * 64 * 8];
    float (*epart)[4] = (float(*)[4])pool;
    float* scratch = pool;

#pragma unroll
    for (int i = 0; i < 8; ++i) {
        int u = i * 512 + tid;
        int row = u >> 6, c16 = u & 63;
        int sr = s0 + row;
        if (sr >= SS) sr = SS - 1;
        const float4* src = (const float4*)&enc[(size_t)(brow0 + sr) * F2H + c16 * 8];
        float4 f0 = src[0], f1 = src[1];
        *(bf16x8*)&Asm[row * 512 + ((c16 ^ (row & 7)) * 8)] = cvt8(f0, f1);
    }
    __syncthreads();

    f32x4 acc[2][4];
#pragma unroll
    for (int mf = 0; mf < 2; ++mf)
#pragma unroll
        for (int nf = 0; nf < 4; ++nf) acc[mf][nf] = (f32x4){0.f, 0.f, 0.f, 0.f};

    const ushort* bbase = wenc_pk + ((size_t)(wc * 4) * 1024 + l) * 8;

#pragma unroll
    for (int t = 0; t < NKC; ++t) {
        bf16x8 af[2], bfr[4];
#pragma unroll
        for (int nf = 0; nf < 4; ++nf)
            bfr[nf] = *(const bf16x8*)(bbase + ((size_t)nf * 1024 + t * 64) * 8);
#pragma unroll
        for (int mf = 0; mf < 2; ++mf) {
            int row = wr * 32 + mf * 16 + ln;
            int c16 = (t * 4 + q) ^ (row & 7);
            af[mf] = *(const bf16x8*)&Asm[row * 512 + c16 * 8];
        }
#pragma unroll
        for (int mf = 0; mf < 2; ++mf)
#pragma unroll
            for (int nf = 0; nf < 4; ++nf)
                acc[mf][nf] = __builtin_amdgcn_mfma_f32_16x16x32_bf16(
                    af[mf], bfr[nf], acc[mf][nf], 0, 0, 0);
    }

    float vv[4];
#pragma unroll
    for (int nf = 0; nf < 4; ++nf) vv[nf] = vvec[wc * 64 + nf * 16 + ln];
    const float* hp = hproj + b * HID;

#pragma unroll
    for (int mf = 0; mf < 2; ++mf) {
#pragma unroll
        for (int r = 0; r < 4; ++r) {
            int row = wr * 32 + mf * 16 + q * 4 + r;
            float p = 0.0f;
#pragma unroll
            for (int nf = 0; nf < 4; ++nf) {
                int col = wc * 64 + nf * 16 + ln;
                p += vv[nf] * ftanh(acc[mf][nf][r] + hp[col]);
            }
#pragma unroll
            for (int off = 8; off >= 1; off >>= 1) p += __shfl_xor(p, off);
            if (ln == 0) epart[row][wc] = p;
        }
    }
    __syncthreads();

    if (tid < 64) {
        int s = s0 + tid;
        float es = (s < SS)
            ? ((epart[tid][0] + epart[tid][1]) + (epart[tid][2] + epart[tid][3]))
            : -1e30f;
        float m = es;
#pragma unroll
        for (int off = 32; off >= 1; off >>= 1) m = fmaxf(m, __shfl_xor(m, off));
        float p = __expf(es - m);
        ps[tid] = p;
        float sum = p;
#pragma unroll
        for (int off = 32; off >= 1; off >>= 1) sum += __shfl_xor(sum, off);
        if (tid == 0) {
            mls[(b * NCHK + chk) * 2 + 0] = m;
            mls[(b * NCHK + chk) * 2 + 1] = sum;
        }
    }
    __syncthreads();

    {
        const int c16 = l;
        float ca[8];
#pragma unroll
        for (int j = 0; j < 8; ++j) ca[j] = 0.f;
#pragma unroll
        for (int r = 0; r < 8; ++r) {
            int row = w * 8 + r;
            float p = ps[row];
            bf16x8 v = *(const bf16x8*)&Asm[row * 512 + ((c16 ^ (row & 7)) * 8)];
#pragma unroll
            for (int j = 0; j < 8; ++j) ca[j] += p * bf2f((ushort)v[j]);
        }
        if (w != 0) {
#pragma unroll
            for (int j = 0; j < 8; ++j) scratch[((w - 1) * 64 + c16) * 8 + j] = ca[j];
        }
        __syncthreads();
        if (w == 0) {
#pragma unroll
            for (int g = 0; g < 7; ++g)
#pragma unroll
                for (int j = 0; j < 8; ++j) ca[j] += scratch[(g * 64 + c16) * 8 + j];
            float4 o0 = {ca[0], ca[1], ca[2], ca[3]};
            float4 o1 = {ca[4], ca[5], ca[6], ca[7]};
            float* dst = ctxp + (size_t)(b * NCHK + chk) * F2H + c16 * 8;
            *(float4*)dst = o0;
            *(float4*)(dst + 4) = o1;
        }
    }
}

// ---------------- K3: combine + projection -> MFMA-fragment-packed bf16 catp ----------------
__global__ __launch_bounds__(256) void k_comb(
    const float* __restrict__ ctxp, const float* __restrict__ mls,
    const float* __restrict__ hvals, const float* __restrict__ proj_W,
    const float* __restrict__ proj_b, ushort* __restrict__ catp_pk)
{
    const int b = blockIdx.x;
    const int j = threadIdx.x;
    __shared__ float cat[768];

    float m[NCHK], lv[NCHK];
#pragma unroll
    for (int c = 0; c < NCHK; ++c) {
        m[c]  = mls[(b * NCHK + c) * 2 + 0];
        lv[c] = mls[(b * NCHK + c) * 2 + 1];
    }
    float ms = m[0];
#pragma unroll
    for (int c = 1; c < NCHK; ++c) ms = fmaxf(ms, m[c]);
    float wgt[NCHK], L = 0.f;
#pragma unroll
    for (int c = 0; c < NCHK; ++c) { wgt[c] = __expf(m[c] - ms); L += lv[c] * wgt[c]; }
    float inv = 1.0f / L;

#pragma unroll
    for (int p = 0; p < 2; ++p) {
        int f = j + p * 256;
        float s = 0.f;
#pragma unroll
        for (int c = 0; c < NCHK; ++c) s += ctxp[((size_t)(b * NCHK + c)) * F2H + f] * wgt[c];
        cat[f] = s * inv;
    }
    cat[F2H + j] = hvals[b * HID + j];
    __syncthreads();

    float acc = proj_b[j];
    const float* wr = proj_W + j * 768;
#pragma unroll 8
    for (int k = 0; k < 768; k += 4) {
        float4 wv = *(const float4*)&wr[k];
        acc += cat[k] * wv.x + cat[k + 1] * wv.y + cat[k + 2] * wv.z + cat[k + 3] * wv.w;
    }
    {
        int u = (b >> 4) * 512 + (j >> 5) * 64 + ((j >> 3) & 3) * 16 + (b & 15);
        catp_pk[u * 8 + (j & 7)] = f2bf(acc);
    }
}

// ---------------- K4: output GEMM — v-tile 32, A register-direct ----------------
__global__ __launch_bounds__(256, 4) void k_out(
    const ushort* __restrict__ catp_pk, const float* __restrict__ out_W,
    const float* __restrict__ out_b, float* __restrict__ wd)
{
    __shared__ ushort Ws[32 * 256];

    const int tid = threadIdx.x;
    const int l = tid & 63;
    const int w = tid >> 6;
    const int q = l >> 4;
    const int ln = l & 15;
    const int wr = w >> 1, wc = w & 1;
    const int v0 = blockIdx.x * 32;

#pragma unroll
    for (int i = 0; i < 4; ++i) {
        int idx = i * 256 + tid;
        int row = idx >> 5, g = idx & 31;
        int vr = v0 + row; if (vr >= VOC) vr = VOC - 1;
        const float4* src = (const float4*)&out_W[(size_t)vr * HID + g * 8];
        float4 f0 = src[0], f1 = src[1];
        *(bf16x8*)&Ws[row * 256 + ((g ^ (row & 7)) * 8)] = cvt8(f0, f1);
    }
    __syncthreads();

    f32x4 acc[2];
    acc[0] = (f32x4){0.f, 0.f, 0.f, 0.f};
    acc[1] = (f32x4){0.f, 0.f, 0.f, 0.f};

    const int vrow = wc * 16 + ln;
    const ushort* abase = catp_pk + ((size_t)(wr * 2) * 512 + l) * 8;

#pragma unroll
    for (int t = 0; t < 8; ++t) {
        bf16x8 af[2];
        af[0] = *(const bf16x8*)(abase + ((size_t)0 * 512 + t * 64) * 8);
        af[1] = *(const bf16x8*)(abase + ((size_t)1 * 512 + t * 64) * 8);
        int gB = (t * 4 + q) ^ (vrow & 7);
        bf16x8 bfr = *(const bf16x8*)&Ws[vrow * 256 + gB * 8];
#pragma unroll
        for (int mf = 0; mf < 2; ++mf)
            acc[mf] = __builtin_amdgcn_mfma_f32_16x16x32_bf16(af[mf], bfr, acc[mf], 0, 0, 0);
    }

    const int v = v0 + vrow;
    if (v < VOC) {
        float bias = out_b[v];
#pragma unroll
        for (int mf = 0; mf < 2; ++mf) {
            int b0 = wr * 32 + mf * 16 + q * 4;
#pragma unroll
            for (int r = 0; r < 4; ++r)
                wd[(size_t)(b0 + r) * VOC + v] = acc[mf][r] + bias;
        }
    }
}

extern "C" void kernel_launch(void* const* d_in, const int* in_sizes, int n_in,
                              void* d_out, int out_size, void* d_ws, size_t ws_size,
                              hipStream_t stream) {
    const int*   word   = (const int*)  d_in[0];
    const float* hidden = (const float*)d_in[1];
    const float* cell   = (const float*)d_in[2];
    const float* enc    = (const float*)d_in[3];
    const float* embed  = (const float*)d_in[5];
    const float* W_ih   = (const float*)d_in[6];
    const float* W_hh   = (const float*)d_in[7];
    const float* b_ih   = (const float*)d_in[8];
    const float* b_hh   = (const float*)d_in[9];
    const float* attn_W = (const float*)d_in[10];
    const float* attn_b = (const float*)d_in[11];
    const float* vvec   = (const float*)d_in[12];
    const float* proj_W = (const float*)d_in[13];
    const float* proj_b = (const float*)d_in[14];
    const float* out_W  = (const float*)d_in[15];
    const float* out_b  = (const float*)d_in[16];

    float* wd  = (float*)d_out;
    float* h_o = wd + (size_t)BB * VOC;
    float* c_o = h_o + BB * HID;

    float* ws    = (float*)d_ws;
    float* part  = ws;                          // 786432
    float* hproj = part + 786432;               // 16384
    float* ctxp  = hproj + 16384;               // 229376
    float* mls   = ctxp + 229376;               // 896
    ushort* wenc_pk = (ushort*)(mls + 896);     // 131072 ushorts
    ushort* catp_pk = wenc_pk + 131072;         // 16384 ushorts

    // MEASUREMENT: k_gates and k_lstm each launched twice (idempotent).
    // Total delta vs r22 (73.9) = warm(k_gates) + warm(k_lstm).
    k_gates<<<dim3(16, KSP + 1), 256, 0, stream>>>(word, hidden, embed, W_ih, W_hh, part, attn_W, wenc_pk);
    k_gates<<<dim3(16, KSP + 1), 256, 0, stream>>>(word, hidden, embed, W_ih, W_hh, part, attn_W, wenc_pk);
    k_lstm<<<dim3(64, 4), 256, 0, stream>>>(part, cell, b_ih, b_hh, attn_W, attn_b, h_o, c_o, hproj);
    k_lstm<<<dim3(64, 4), 256, 0, stream>>>(part, cell, b_ih, b_hh, attn_W, attn_b, h_o, c_o, hproj);
    k_attn<<<BB * NCHK, 512, 0, stream>>>(enc, wenc_pk, hproj, vvec, ctxp, mls);
    k_comb<<<64, 256, 0, stream>>>(ctxp, mls, h_o, proj_W, proj_b, catp_pk);
    k_out<<<1563, 256, 0, stream>>>(catp_pk, out_W, out_b, wd);
}

// Round 24
// 78.458 us; speedup vs baseline: 1.0538x; 1.0538x over previous
//
#include <hip/hip_runtime.h>
#include <hip/hip_bf16.h>
#include <math.h>

#define BB 64
#define SS 400
#define F2H 512
#define HID 256
#define EMB 128
#define NGATE 1024
#define VOC 50000
#define CH 64
#define NCHK 7
#define NKC 16
#define KSP 12

typedef short bf16x8 __attribute__((ext_vector_type(8)));
typedef float f32x4 __attribute__((ext_vector_type(4)));

__device__ __forceinline__ float sigm(float x) { return 1.0f / (1.0f + __expf(-x)); }

__device__ __forceinline__ float ftanh(float x) {
    float e = __expf(2.0f * x);
    return 1.0f - 2.0f / (e + 1.0f);
}

__device__ __forceinline__ ushort f2bf(float x) {
    uint32_t u = __float_as_uint(x);
    uint32_t r = u + 0x7FFFu + ((u >> 16) & 1u);
    return (ushort)(r >> 16);
}

__device__ __forceinline__ float bf2f(ushort u) {
    return __uint_as_float(((uint32_t)u) << 16);
}

__device__ __forceinline__ bf16x8 cvt8(float4 a, float4 b) {
    __hip_bfloat162 p0 = __float22bfloat162_rn({a.x, a.y});
    __hip_bfloat162 p1 = __float22bfloat162_rn({a.z, a.w});
    __hip_bfloat162 p2 = __float22bfloat162_rn({b.x, b.y});
    __hip_bfloat162 p3 = __float22bfloat162_rn({b.z, b.w});
    union { bf16x8 v; uint32_t u[4]; } r;
    r.u[0] = *(uint32_t*)&p0;
    r.u[1] = *(uint32_t*)&p1;
    r.u[2] = *(uint32_t*)&p2;
    r.u[3] = *(uint32_t*)&p3;
    return r.v;
}

// ---------------- K1a: gates GEMM (12-way k-split) + wenc pack + enc->bf16 convert ----------------
// grid (16, 113): y<12 gates; y==12 wenc pack; y>=13 enc conversion (1600 blocks)
__global__ __launch_bounds__(256) void k_gates(
    const int* __restrict__ word, const float* __restrict__ hidden,
    const float* __restrict__ embed, const float* __restrict__ W_ih,
    const float* __restrict__ W_hh, float* __restrict__ part,
    const float* __restrict__ attn_W, ushort* __restrict__ wenc_pk,
    const float* __restrict__ enc, ushort* __restrict__ enc_bf)
{
    const int gt = blockIdx.x;
    const int ks = blockIdx.y;
    const int tid = threadIdx.x;

    if (ks > KSP) {   // enc fp32 -> bf16 (1600 blocks x 8192 floats)
        int cb = (ks - KSP - 1) * 16 + gt;
        size_t i0 = (size_t)cb * 2048 + tid;
        const float4* src = (const float4*)enc;
#pragma unroll
        for (int r = 0; r < 8; ++r) {
            size_t i = i0 + (size_t)r * 256;
            float4 f = src[i];
            ushort4 o = make_ushort4(f2bf(f.x), f2bf(f.y), f2bf(f.z), f2bf(f.w));
            ((ushort4*)enc_bf)[i] = o;
        }
        return;
    }

    if (ks == KSP) {   // wenc fragment-packed prep
#pragma unroll
        for (int r = 0; r < 4; ++r) {
            int u = gt * 1024 + r * 256 + tid;
            int l = u & 63;
            int t = (u >> 6) & 15;
            int nt = u >> 10;
            int n = nt * 16 + (l & 15);
            int k0 = t * 32 + (l >> 4) * 8;
            const float4* src = (const float4*)&attn_W[n * 768 + k0];
            float4 f0 = src[0], f1 = src[1];
            *(bf16x8*)&wenc_pk[(size_t)u * 8] = cvt8(f0, f1);
        }
        return;
    }

    __shared__ float As[32 * 68];
    __shared__ float Bs[32 * 68];
    const int g0 = gt * 64;
    const int kc = ks * 32;
    float acc[4][4];
#pragma unroll
    for (int i = 0; i < 4; ++i)
#pragma unroll
        for (int j = 0; j < 4; ++j) acc[i][j] = 0.0f;

    const int tb = tid >> 4;
    const int tg = tid & 15;
    const int srow = tid >> 3;
    const int skk = (tid & 7) * 4;

#pragma unroll
    for (int p = 0; p < 2; ++p) {
        int rr = srow + p * 32;
        int gk = kc + skk;
        float4 f;
        if (gk < EMB) {
            int w = word[rr];
            f = *(const float4*)&embed[w * EMB + gk];
        } else {
            f = *(const float4*)&hidden[rr * HID + gk - EMB];
        }
        As[(skk + 0) * 68 + rr] = f.x;
        As[(skk + 1) * 68 + rr] = f.y;
        As[(skk + 2) * 68 + rr] = f.z;
        As[(skk + 3) * 68 + rr] = f.w;
    }
#pragma unroll
    for (int p = 0; p < 2; ++p) {
        int nn = srow + p * 32;
        int g = g0 + nn;
        int gk = kc + skk;
        float4 f;
        if (gk < EMB) f = *(const float4*)&W_ih[g * EMB + gk];
        else          f = *(const float4*)&W_hh[g * HID + gk - EMB];
        Bs[(skk + 0) * 68 + nn] = f.x;
        Bs[(skk + 1) * 68 + nn] = f.y;
        Bs[(skk + 2) * 68 + nn] = f.z;
        Bs[(skk + 3) * 68 + nn] = f.w;
    }
    __syncthreads();
#pragma unroll 8
    for (int k = 0; k < 32; ++k) {
        float4 a = *(const float4*)&As[k * 68 + tb * 4];
        float4 b = *(const float4*)&Bs[k * 68 + tg * 4];
        float av[4] = {a.x, a.y, a.z, a.w};
        float bv[4] = {b.x, b.y, b.z, b.w};
#pragma unroll
        for (int i = 0; i < 4; ++i)
#pragma unroll
            for (int j = 0; j < 4; ++j) acc[i][j] += av[i] * bv[j];
    }
    float* dst = part + ks * (BB * NGATE);
#pragma unroll
    for (int i = 0; i < 4; ++i) {
        int b = tb * 4 + i;
        float4 o = {acc[i][0], acc[i][1], acc[i][2], acc[i][3]};
        *(float4*)&dst[b * NGATE + g0 + tg * 4] = o;
    }
}

// ---------------- K1b: LSTM pointwise + hproj (4-way col-split) ----------------
__global__ __launch_bounds__(256) void k_lstm(
    const float* __restrict__ part, const float* __restrict__ cell,
    const float* __restrict__ b_ih, const float* __restrict__ b_hh,
    const float* __restrict__ attn_W, const float* __restrict__ attn_b,
    float* __restrict__ h_out, float* __restrict__ c_out, float* __restrict__ hproj)
{
    const int b = blockIdx.x;
    const int qg = blockIdx.y;
    const int u = threadIdx.x;
    __shared__ float hrow[HID];

    float gi = b_ih[u] + b_hh[u];
    float gf = b_ih[u + 256] + b_hh[u + 256];
    float gg = b_ih[u + 512] + b_hh[u + 512];
    float go = b_ih[u + 768] + b_hh[u + 768];
#pragma unroll
    for (int ks = 0; ks < KSP; ++ks) {
        const float* p = part + ks * (BB * NGATE) + b * NGATE;
        gi += p[u];
        gf += p[u + 256];
        gg += p[u + 512];
        go += p[u + 768];
    }
    float c = sigm(gf) * cell[b * HID + u] + sigm(gi) * tanhf(gg);
    float h = tanhf(sigm(go) * tanhf(c));
    if (qg == 0) {
        c_out[b * HID + u] = c;
        h_out[b * HID + u] = h;
    }
    hrow[u] = h;
    __syncthreads();

    const int col = qg * 64 + (u >> 2);
    const int kq = u & 3;
    const float* wr = attn_W + col * 768 + 512 + kq * 64;
    const float* hr = hrow + kq * 64;
    float acc = 0.f;
#pragma unroll 8
    for (int k = 0; k < 64; k += 4) {
        float4 wv = *(const float4*)&wr[k];
        acc += hr[k] * wv.x + hr[k + 1] * wv.y + hr[k + 2] * wv.z + hr[k + 3] * wv.w;
    }
    acc += __shfl_xor(acc, 1);
    acc += __shfl_xor(acc, 2);
    if (kq == 0) hproj[b * HID + col] = acc + attn_b[col];
}

// ---------------- K2: fused attention — bf16 enc input ----------------
__global__ __launch_bounds__(512, 4) void k_attn(
    const ushort* __restrict__ enc_bf, const ushort* __restrict__ wenc_pk,
    const float* __restrict__ hproj, const float* __restrict__ vvec,
    float* __restrict__ ctxp, float* __restrict__ mls)
{
    const int b   = blockIdx.x / NCHK;
    const int chk = blockIdx.x % NCHK;
    const int s0  = chk * CH;
    const int tid = threadIdx.x;
    const int l = tid & 63;
    const int w = tid >> 6;
    const int wr = w >> 2, wc = w & 3;
    const int brow0 = b * SS;
    const int ln = l & 15, q = l >> 4;

    __shared__ ushort Asm[CH * 512];
    __shared__ float ps[CH];
    __shared__ float pool[7 * 64 * 8];
    float (*epart)[4] = (float(*)[4])pool;
    float* scratch = pool;

    // A stage: copy bf16 rows (1 KB/row), 16B per thread-iter, swizzled store
#pragma unroll
    for (int i = 0; i < 8; ++i) {
        int u = i * 512 + tid;
        int row = u >> 6, c16 = u & 63;
        int sr = s0 + row;
        if (sr >= SS) sr = SS - 1;
        bf16x8 v = *(const bf16x8*)&enc_bf[(size_t)(brow0 + sr) * F2H + c16 * 8];
        *(bf16x8*)&Asm[row * 512 + ((c16 ^ (row & 7)) * 8)] = v;
    }
    __syncthreads();

    f32x4 acc[2][4];
#pragma unroll
    for (int mf = 0; mf < 2; ++mf)
#pragma unroll
        for (int nf = 0; nf < 4; ++nf) acc[mf][nf] = (f32x4){0.f, 0.f, 0.f, 0.f};

    const ushort* bbase = wenc_pk + ((size_t)(wc * 4) * 1024 + l) * 8;

#pragma unroll
    for (int t = 0; t < NKC; ++t) {
        bf16x8 af[2], bfr[4];
#pragma unroll
        for (int nf = 0; nf < 4; ++nf)
            bfr[nf] = *(const bf16x8*)(bbase + ((size_t)nf * 1024 + t * 64) * 8);
#pragma unroll
        for (int mf = 0; mf < 2; ++mf) {
            int row = wr * 32 + mf * 16 + ln;
            int c16 = (t * 4 + q) ^ (row & 7);
            af[mf] = *(const bf16x8*)&Asm[row * 512 + c16 * 8];
        }
#pragma unroll
        for (int mf = 0; mf < 2; ++mf)
#pragma unroll
            for (int nf = 0; nf < 4; ++nf)
                acc[mf][nf] = __builtin_amdgcn_mfma_f32_16x16x32_bf16(
                    af[mf], bfr[nf], acc[mf][nf], 0, 0, 0);
    }

    float vv[4];
#pragma unroll
    for (int nf = 0; nf < 4; ++nf) vv[nf] = vvec[wc * 64 + nf * 16 + ln];
    const float* hp = hproj + b * HID;

#pragma unroll
    for (int mf = 0; mf < 2; ++mf) {
#pragma unroll
        for (int r = 0; r < 4; ++r) {
            int row = wr * 32 + mf * 16 + q * 4 + r;
            float p = 0.0f;
#pragma unroll
            for (int nf = 0; nf < 4; ++nf) {
                int col = wc * 64 + nf * 16 + ln;
                p += vv[nf] * ftanh(acc[mf][nf][r] + hp[col]);
            }
#pragma unroll
            for (int off = 8; off >= 1; off >>= 1) p += __shfl_xor(p, off);
            if (ln == 0) epart[row][wc] = p;
        }
    }
    __syncthreads();

    if (tid < 64) {
        int s = s0 + tid;
        float es = (s < SS)
            ? ((epart[tid][0] + epart[tid][1]) + (epart[tid][2] + epart[tid][3]))
            : -1e30f;
        float m = es;
#pragma unroll
        for (int off = 32; off >= 1; off >>= 1) m = fmaxf(m, __shfl_xor(m, off));
        float p = __expf(es - m);
        ps[tid] = p;
        float sum = p;
#pragma unroll
        for (int off = 32; off >= 1; off >>= 1) sum += __shfl_xor(sum, off);
        if (tid == 0) {
            mls[(b * NCHK + chk) * 2 + 0] = m;
            mls[(b * NCHK + chk) * 2 + 1] = sum;
        }
    }
    __syncthreads();

    {
        const int c16 = l;
        float ca[8];
#pragma unroll
        for (int j = 0; j < 8; ++j) ca[j] = 0.f;
#pragma unroll
        for (int r = 0; r < 8; ++r) {
            int row = w * 8 + r;
            float p = ps[row];
            bf16x8 v = *(const bf16x8*)&Asm[row * 512 + ((c16 ^ (row & 7)) * 8)];
#pragma unroll
            for (int j = 0; j < 8; ++j) ca[j] += p * bf2f((ushort)v[j]);
        }
        if (w != 0) {
#pragma unroll
            for (int j = 0; j < 8; ++j) scratch[((w - 1) * 64 + c16) * 8 + j] = ca[j];
        }
        __syncthreads();
        if (w == 0) {
#pragma unroll
            for (int g = 0; g < 7; ++g)
#pragma unroll
                for (int j = 0; j < 8; ++j) ca[j] += scratch[(g * 64 + c16) * 8 + j];
            float4 o0 = {ca[0], ca[1], ca[2], ca[3]};
            float4 o1 = {ca[4], ca[5], ca[6], ca[7]};
            float* dst = ctxp + (size_t)(b * NCHK + chk) * F2H + c16 * 8;
            *(float4*)dst = o0;
            *(float4*)(dst + 4) = o1;
        }
    }
}

// ---------------- K3: combine + projection -> MFMA-fragment-packed bf16 catp ----------------
__global__ __launch_bounds__(256) void k_comb(
    const float* __restrict__ ctxp, const float* __restrict__ mls,
    const float* __restrict__ hvals, const float* __restrict__ proj_W,
    const float* __restrict__ proj_b, ushort* __restrict__ catp_pk)
{
    const int b = blockIdx.x;
    const int j = threadIdx.x;
    __shared__ float cat[768];

    float m[NCHK], lv[NCHK];
#pragma unroll
    for (int c = 0; c < NCHK; ++c) {
        m[c]  = mls[(b * NCHK + c) * 2 + 0];
        lv[c] = mls[(b * NCHK + c) * 2 + 1];
    }
    float ms = m[0];
#pragma unroll
    for (int c = 1; c < NCHK; ++c) ms = fmaxf(ms, m[c]);
    float wgt[NCHK], L = 0.f;
#pragma unroll
    for (int c = 0; c < NCHK; ++c) { wgt[c] = __expf(m[c] - ms); L += lv[c] * wgt[c]; }
    float inv = 1.0f / L;

#pragma unroll
    for (int p = 0; p < 2; ++p) {
        int f = j + p * 256;
        float s = 0.f;
#pragma unroll
        for (int c = 0; c < NCHK; ++c) s += ctxp[((size_t)(b * NCHK + c)) * F2H + f] * wgt[c];
        cat[f] = s * inv;
    }
    cat[F2H + j] = hvals[b * HID + j];
    __syncthreads();

    float acc = proj_b[j];
    const float* wr = proj_W + j * 768;
#pragma unroll 8
    for (int k = 0; k < 768; k += 4) {
        float4 wv = *(const float4*)&wr[k];
        acc += cat[k] * wv.x + cat[k + 1] * wv.y + cat[k + 2] * wv.z + cat[k + 3] * wv.w;
    }
    {
        int u = (b >> 4) * 512 + (j >> 5) * 64 + ((j >> 3) & 3) * 16 + (b & 15);
        catp_pk[u * 8 + (j & 7)] = f2bf(acc);
    }
}

// ---------------- K4: output GEMM — v-tile 32, A register-direct ----------------
__global__ __launch_bounds__(256, 4) void k_out(
    const ushort* __restrict__ catp_pk, const float* __restrict__ out_W,
    const float* __restrict__ out_b, float* __restrict__ wd)
{
    __shared__ ushort Ws[32 * 256];

    const int tid = threadIdx.x;
    const int l = tid & 63;
    const int w = tid >> 6;
    const int q = l >> 4;
    const int ln = l & 15;
    const int wr = w >> 1, wc = w & 1;
    const int v0 = blockIdx.x * 32;

#pragma unroll
    for (int i = 0; i < 4; ++i) {
        int idx = i * 256 + tid;
        int row = idx >> 5, g = idx & 31;
        int vr = v0 + row; if (vr >= VOC) vr = VOC - 1;
        const float4* src = (const float4*)&out_W[(size_t)vr * HID + g * 8];
        float4 f0 = src[0], f1 = src[1];
        *(bf16x8*)&Ws[row * 256 + ((g ^ (row & 7)) * 8)] = cvt8(f0, f1);
    }
    __syncthreads();

    f32x4 acc[2];
    acc[0] = (f32x4){0.f, 0.f, 0.f, 0.f};
    acc[1] = (f32x4){0.f, 0.f, 0.f, 0.f};

    const int vrow = wc * 16 + ln;
    const ushort* abase = catp_pk + ((size_t)(wr * 2) * 512 + l) * 8;

#pragma unroll
    for (int t = 0; t < 8; ++t) {
        bf16x8 af[2];
        af[0] = *(const bf16x8*)(abase + ((size_t)0 * 512 + t * 64) * 8);
        af[1] = *(const bf16x8*)(abase + ((size_t)1 * 512 + t * 64) * 8);
        int gB = (t * 4 + q) ^ (vrow & 7);
        bf16x8 bfr = *(const bf16x8*)&Ws[vrow * 256 + gB * 8];
#pragma unroll
        for (int mf = 0; mf < 2; ++mf)
            acc[mf] = __builtin_amdgcn_mfma_f32_16x16x32_bf16(af[mf], bfr, acc[mf], 0, 0, 0);
    }

    const int v = v0 + vrow;
    if (v < VOC) {
        float bias = out_b[v];
#pragma unroll
        for (int mf = 0; mf < 2; ++mf) {
            int b0 = wr * 32 + mf * 16 + q * 4;
#pragma unroll
            for (int r = 0; r < 4; ++r)
                wd[(size_t)(b0 + r) * VOC + v] = acc[mf][r] + bias;
        }
    }
}

extern "C" void kernel_launch(void* const* d_in, const int* in_sizes, int n_in,
                              void* d_out, int out_size, void* d_ws, size_t ws_size,
                              hipStream_t stream) {
    const int*   word   = (const int*)  d_in[0];
    const float* hidden = (const float*)d_in[1];
    const float* cell   = (const float*)d_in[2];
    const float* enc    = (const float*)d_in[3];
    const float* embed  = (const float*)d_in[5];
    const float* W_ih   = (const float*)d_in[6];
    const float* W_hh   = (const float*)d_in[7];
    const float* b_ih   = (const float*)d_in[8];
    const float* b_hh   = (const float*)d_in[9];
    const float* attn_W = (const float*)d_in[10];
    const float* attn_b = (const float*)d_in[11];
    const float* vvec   = (const float*)d_in[12];
    const float* proj_W = (const float*)d_in[13];
    const float* proj_b = (const float*)d_in[14];
    const float* out_W  = (const float*)d_in[15];
    const float* out_b  = (const float*)d_in[16];

    float* wd  = (float*)d_out;
    float* h_o = wd + (size_t)BB * VOC;
    float* c_o = h_o + BB * HID;

    float* ws    = (float*)d_ws;
    float* part  = ws;                          // 786432
    float* hproj = part + 786432;               // 16384
    float* ctxp  = hproj + 16384;               // 229376
    float* mls   = ctxp + 229376;               // 896
    ushort* wenc_pk = (ushort*)(mls + 896);     // 131072 ushorts
    ushort* catp_pk = wenc_pk + 131072;         // 16384 ushorts
    ushort* enc_bf  = catp_pk + 16384;          // 13,107,200 ushorts

    k_gates<<<dim3(16, KSP + 101), 256, 0, stream>>>(word, hidden, embed, W_ih, W_hh, part,
                                                     attn_W, wenc_pk, enc, enc_bf);
    k_lstm<<<dim3(64, 4), 256, 0, stream>>>(part, cell, b_ih, b_hh, attn_W, attn_b, h_o, c_o, hproj);
    k_attn<<<BB * NCHK, 512, 0, stream>>>(enc_bf, wenc_pk, hproj, vvec, ctxp, mls);
    k_comb<<<64, 256, 0, stream>>>(ctxp, mls, h_o, proj_W, proj_b, catp_pk);
    k_out<<<1563, 256, 0, stream>>>(catp_pk, out_W, out_b, wd);
}

// Round 25
// 73.939 us; speedup vs baseline: 1.1182x; 1.0611x over previous
//
#include <hip/hip_runtime.h>
#include <hip/hip_bf16.h>
#include <math.h>

#define BB 64
#define SS 400
#define F2H 512
#define HID 256
#define EMB 128
#define NGATE 1024
#define VOC 50000
#define CH 64
#define NCHK 7
#define NKC 16
#define KSP 12

typedef short bf16x8 __attribute__((ext_vector_type(8)));
typedef float f32x4 __attribute__((ext_vector_type(4)));

__device__ __forceinline__ float sigm(float x) { return 1.0f / (1.0f + __expf(-x)); }

__device__ __forceinline__ float ftanh(float x) {
    float e = __expf(2.0f * x);
    return 1.0f - 2.0f / (e + 1.0f);
}

__device__ __forceinline__ ushort f2bf(float x) {
    uint32_t u = __float_as_uint(x);
    uint32_t r = u + 0x7FFFu + ((u >> 16) & 1u);
    return (ushort)(r >> 16);
}

__device__ __forceinline__ float bf2f(ushort u) {
    return __uint_as_float(((uint32_t)u) << 16);
}

__device__ __forceinline__ bf16x8 cvt8(float4 a, float4 b) {
    __hip_bfloat162 p0 = __float22bfloat162_rn({a.x, a.y});
    __hip_bfloat162 p1 = __float22bfloat162_rn({a.z, a.w});
    __hip_bfloat162 p2 = __float22bfloat162_rn({b.x, b.y});
    __hip_bfloat162 p3 = __float22bfloat162_rn({b.z, b.w});
    union { bf16x8 v; uint32_t u[4]; } r;
    r.u[0] = *(uint32_t*)&p0;
    r.u[1] = *(uint32_t*)&p1;
    r.u[2] = *(uint32_t*)&p2;
    r.u[3] = *(uint32_t*)&p3;
    return r.v;
}

// ---------------- K1a: gates partial GEMM (12-way k-split) + wenc pack ----------------
__global__ __launch_bounds__(256) void k_gates(
    const int* __restrict__ word, const float* __restrict__ hidden,
    const float* __restrict__ embed, const float* __restrict__ W_ih,
    const float* __restrict__ W_hh, float* __restrict__ part,
    const float* __restrict__ attn_W, ushort* __restrict__ wenc_pk)
{
    const int gt = blockIdx.x;
    const int ks = blockIdx.y;
    const int tid = threadIdx.x;

    if (ks == KSP) {
#pragma unroll
        for (int r = 0; r < 4; ++r) {
            int u = gt * 1024 + r * 256 + tid;
            int l = u & 63;
            int t = (u >> 6) & 15;
            int nt = u >> 10;
            int n = nt * 16 + (l & 15);
            int k0 = t * 32 + (l >> 4) * 8;
            const float4* src = (const float4*)&attn_W[n * 768 + k0];
            float4 f0 = src[0], f1 = src[1];
            *(bf16x8*)&wenc_pk[(size_t)u * 8] = cvt8(f0, f1);
        }
        return;
    }

    __shared__ float As[32 * 68];
    __shared__ float Bs[32 * 68];
    const int g0 = gt * 64;
    const int kc = ks * 32;
    float acc[4][4];
#pragma unroll
    for (int i = 0; i < 4; ++i)
#pragma unroll
        for (int j = 0; j < 4; ++j) acc[i][j] = 0.0f;

    const int tb = tid >> 4;
    const int tg = tid & 15;
    const int srow = tid >> 3;
    const int skk = (tid & 7) * 4;

#pragma unroll
    for (int p = 0; p < 2; ++p) {
        int rr = srow + p * 32;
        int gk = kc + skk;
        float4 f;
        if (gk < EMB) {
            int w = word[rr];
            f = *(const float4*)&embed[w * EMB + gk];
        } else {
            f = *(const float4*)&hidden[rr * HID + gk - EMB];
        }
        As[(skk + 0) * 68 + rr] = f.x;
        As[(skk + 1) * 68 + rr] = f.y;
        As[(skk + 2) * 68 + rr] = f.z;
        As[(skk + 3) * 68 + rr] = f.w;
    }
#pragma unroll
    for (int p = 0; p < 2; ++p) {
        int nn = srow + p * 32;
        int g = g0 + nn;
        int gk = kc + skk;
        float4 f;
        if (gk < EMB) f = *(const float4*)&W_ih[g * EMB + gk];
        else          f = *(const float4*)&W_hh[g * HID + gk - EMB];
        Bs[(skk + 0) * 68 + nn] = f.x;
        Bs[(skk + 1) * 68 + nn] = f.y;
        Bs[(skk + 2) * 68 + nn] = f.z;
        Bs[(skk + 3) * 68 + nn] = f.w;
    }
    __syncthreads();
#pragma unroll 8
    for (int k = 0; k < 32; ++k) {
        float4 a = *(const float4*)&As[k * 68 + tb * 4];
        float4 b = *(const float4*)&Bs[k * 68 + tg * 4];
        float av[4] = {a.x, a.y, a.z, a.w};
        float bv[4] = {b.x, b.y, b.z, b.w};
#pragma unroll
        for (int i = 0; i < 4; ++i)
#pragma unroll
            for (int j = 0; j < 4; ++j) acc[i][j] += av[i] * bv[j];
    }
    float* dst = part + ks * (BB * NGATE);
#pragma unroll
    for (int i = 0; i < 4; ++i) {
        int b = tb * 4 + i;
        float4 o = {acc[i][0], acc[i][1], acc[i][2], acc[i][3]};
        *(float4*)&dst[b * NGATE + g0 + tg * 4] = o;
    }
}

// ---------------- K1b: LSTM pointwise + hproj (4-way col-split) ----------------
__global__ __launch_bounds__(256) void k_lstm(
    const float* __restrict__ part, const float* __restrict__ cell,
    const float* __restrict__ b_ih, const float* __restrict__ b_hh,
    const float* __restrict__ attn_W, const float* __restrict__ attn_b,
    float* __restrict__ h_out, float* __restrict__ c_out, float* __restrict__ hproj)
{
    const int b = blockIdx.x;
    const int qg = blockIdx.y;
    const int u = threadIdx.x;
    __shared__ float hrow[HID];

    float gi = b_ih[u] + b_hh[u];
    float gf = b_ih[u + 256] + b_hh[u + 256];
    float gg = b_ih[u + 512] + b_hh[u + 512];
    float go = b_ih[u + 768] + b_hh[u + 768];
#pragma unroll
    for (int ks = 0; ks < KSP; ++ks) {
        const float* p = part + ks * (BB * NGATE) + b * NGATE;
        gi += p[u];
        gf += p[u + 256];
        gg += p[u + 512];
        go += p[u + 768];
    }
    float c = sigm(gf) * cell[b * HID + u] + sigm(gi) * tanhf(gg);
    float h = tanhf(sigm(go) * tanhf(c));
    if (qg == 0) {
        c_out[b * HID + u] = c;
        h_out[b * HID + u] = h;
    }
    hrow[u] = h;
    __syncthreads();

    const int col = qg * 64 + (u >> 2);
    const int kq = u & 3;
    const float* wr = attn_W + col * 768 + 512 + kq * 64;
    const float* hr = hrow + kq * 64;
    float acc = 0.f;
#pragma unroll 8
    for (int k = 0; k < 64; k += 4) {
        float4 wv = *(const float4*)&wr[k];
        acc += hr[k] * wv.x + hr[k + 1] * wv.y + hr[k + 2] * wv.z + hr[k + 3] * wv.w;
    }
    acc += __shfl_xor(acc, 1);
    acc += __shfl_xor(acc, 2);
    if (kq == 0) hproj[b * HID + col] = acc + attn_b[col];
}

// ---------------- K2: fused attention ----------------
__global__ __launch_bounds__(512, 4) void k_attn(
    const float* __restrict__ enc, const ushort* __restrict__ wenc_pk,
    const float* __restrict__ hproj, const float* __restrict__ vvec,
    float* __restrict__ ctxp, float* __restrict__ mls)
{
    const int b   = blockIdx.x / NCHK;
    const int chk = blockIdx.x % NCHK;
    const int s0  = chk * CH;
    const int tid = threadIdx.x;
    const int l = tid & 63;
    const int w = tid >> 6;
    const int wr = w >> 2, wc = w & 3;
    const int brow0 = b * SS;
    const int ln = l & 15, q = l >> 4;

    __shared__ ushort Asm[CH * 512];
    __shared__ float ps[CH];
    __shared__ float pool[7 * 64 * 8];
    float (*epart)[4] = (float(*)[4])pool;
    float* scratch = pool;

#pragma unroll
    for (int i = 0; i < 8; ++i) {
        int u = i * 512 + tid;
        int row = u >> 6, c16 = u & 63;
        int sr = s0 + row;
        if (sr >= SS) sr = SS - 1;
        const float4* src = (const float4*)&enc[(size_t)(brow0 + sr) * F2H + c16 * 8];
        float4 f0 = src[0], f1 = src[1];
        *(bf16x8*)&Asm[row * 512 + ((c16 ^ (row & 7)) * 8)] = cvt8(f0, f1);
    }
    __syncthreads();

    f32x4 acc[2][4];
#pragma unroll
    for (int mf = 0; mf < 2; ++mf)
#pragma unroll
        for (int nf = 0; nf < 4; ++nf) acc[mf][nf] = (f32x4){0.f, 0.f, 0.f, 0.f};

    const ushort* bbase = wenc_pk + ((size_t)(wc * 4) * 1024 + l) * 8;

#pragma unroll
    for (int t = 0; t < NKC; ++t) {
        bf16x8 af[2], bfr[4];
#pragma unroll
        for (int nf = 0; nf < 4; ++nf)
            bfr[nf] = *(const bf16x8*)(bbase + ((size_t)nf * 1024 + t * 64) * 8);
#pragma unroll
        for (int mf = 0; mf < 2; ++mf) {
            int row = wr * 32 + mf * 16 + ln;
            int c16 = (t * 4 + q) ^ (row & 7);
            af[mf] = *(const bf16x8*)&Asm[row * 512 + c16 * 8];
        }
#pragma unroll
        for (int mf = 0; mf < 2; ++mf)
#pragma unroll
            for (int nf = 0; nf < 4; ++nf)
                acc[mf][nf] = __builtin_amdgcn_mfma_f32_16x16x32_bf16(
                    af[mf], bfr[nf], acc[mf][nf], 0, 0, 0);
    }

    float vv[4];
#pragma unroll
    for (int nf = 0; nf < 4; ++nf) vv[nf] = vvec[wc * 64 + nf * 16 + ln];
    const float* hp = hproj + b * HID;

#pragma unroll
    for (int mf = 0; mf < 2; ++mf) {
#pragma unroll
        for (int r = 0; r < 4; ++r) {
            int row = wr * 32 + mf * 16 + q * 4 + r;
            float p = 0.0f;
#pragma unroll
            for (int nf = 0; nf < 4; ++nf) {
                int col = wc * 64 + nf * 16 + ln;
                p += vv[nf] * ftanh(acc[mf][nf][r] + hp[col]);
            }
#pragma unroll
            for (int off = 8; off >= 1; off >>= 1) p += __shfl_xor(p, off);
            if (ln == 0) epart[row][wc] = p;
        }
    }
    __syncthreads();

    if (tid < 64) {
        int s = s0 + tid;
        float es = (s < SS)
            ? ((epart[tid][0] + epart[tid][1]) + (epart[tid][2] + epart[tid][3]))
            : -1e30f;
        float m = es;
#pragma unroll
        for (int off = 32; off >= 1; off >>= 1) m = fmaxf(m, __shfl_xor(m, off));
        float p = __expf(es - m);
        ps[tid] = p;
        float sum = p;
#pragma unroll
        for (int off = 32; off >= 1; off >>= 1) sum += __shfl_xor(sum, off);
        if (tid == 0) {
            mls[(b * NCHK + chk) * 2 + 0] = m;
            mls[(b * NCHK + chk) * 2 + 1] = sum;
        }
    }
    __syncthreads();

    {
        const int c16 = l;
        float ca[8];
#pragma unroll
        for (int j = 0; j < 8; ++j) ca[j] = 0.f;
#pragma unroll
        for (int r = 0; r < 8; ++r) {
            int row = w * 8 + r;
            float p = ps[row];
            bf16x8 v = *(const bf16x8*)&Asm[row * 512 + ((c16 ^ (row & 7)) * 8)];
#pragma unroll
            for (int j = 0; j < 8; ++j) ca[j] += p * bf2f((ushort)v[j]);
        }
        if (w != 0) {
#pragma unroll
            for (int j = 0; j < 8; ++j) scratch[((w - 1) * 64 + c16) * 8 + j] = ca[j];
        }
        __syncthreads();
        if (w == 0) {
#pragma unroll
            for (int g = 0; g < 7; ++g)
#pragma unroll
                for (int j = 0; j < 8; ++j) ca[j] += scratch[(g * 64 + c16) * 8 + j];
            float4 o0 = {ca[0], ca[1], ca[2], ca[3]};
            float4 o1 = {ca[4], ca[5], ca[6], ca[7]};
            float* dst = ctxp + (size_t)(b * NCHK + chk) * F2H + c16 * 8;
            *(float4*)dst = o0;
            *(float4*)(dst + 4) = o1;
        }
    }
}

// ---------------- K3: combine + projection -> MFMA-fragment-packed bf16 catp ----------------
__global__ __launch_bounds__(256) void k_comb(
    const float* __restrict__ ctxp, const float* __restrict__ mls,
    const float* __restrict__ hvals, const float* __restrict__ proj_W,
    const float* __restrict__ proj_b, ushort* __restrict__ catp_pk)
{
    const int b = blockIdx.x;
    const int j = threadIdx.x;
    __shared__ float cat[768];

    float m[NCHK], lv[NCHK];
#pragma unroll
    for (int c = 0; c < NCHK; ++c) {
        m[c]  = mls[(b * NCHK + c) * 2 + 0];
        lv[c] = mls[(b * NCHK + c) * 2 + 1];
    }
    float ms = m[0];
#pragma unroll
    for (int c = 1; c < NCHK; ++c) ms = fmaxf(ms, m[c]);
    float wgt[NCHK], L = 0.f;
#pragma unroll
    for (int c = 0; c < NCHK; ++c) { wgt[c] = __expf(m[c] - ms); L += lv[c] * wgt[c]; }
    float inv = 1.0f / L;

#pragma unroll
    for (int p = 0; p < 2; ++p) {
        int f = j + p * 256;
        float s = 0.f;
#pragma unroll
        for (int c = 0; c < NCHK; ++c) s += ctxp[((size_t)(b * NCHK + c)) * F2H + f] * wgt[c];
        cat[f] = s * inv;
    }
    cat[F2H + j] = hvals[b * HID + j];
    __syncthreads();

    float acc = proj_b[j];
    const float* wr = proj_W + j * 768;
#pragma unroll 8
    for (int k = 0; k < 768; k += 4) {
        float4 wv = *(const float4*)&wr[k];
        acc += cat[k] * wv.x + cat[k + 1] * wv.y + cat[k + 2] * wv.z + cat[k + 3] * wv.w;
    }
    {
        int u = (b >> 4) * 512 + (j >> 5) * 64 + ((j >> 3) & 3) * 16 + (b & 15);
        catp_pk[u * 8 + (j & 7)] = f2bf(acc);
    }
}

// ---------------- K4: output GEMM — v-tile 32, A register-direct ----------------
__global__ __launch_bounds__(256, 4) void k_out(
    const ushort* __restrict__ catp_pk, const float* __restrict__ out_W,
    const float* __restrict__ out_b, float* __restrict__ wd)
{
    __shared__ ushort Ws[32 * 256];

    const int tid = threadIdx.x;
    const int l = tid & 63;
    const int w = tid >> 6;
    const int q = l >> 4;
    const int ln = l & 15;
    const int wr = w >> 1, wc = w & 1;
    const int v0 = blockIdx.x * 32;

#pragma unroll
    for (int i = 0; i < 4; ++i) {
        int idx = i * 256 + tid;
        int row = idx >> 5, g = idx & 31;
        int vr = v0 + row; if (vr >= VOC) vr = VOC - 1;
        const float4* src = (const float4*)&out_W[(size_t)vr * HID + g * 8];
        float4 f0 = src[0], f1 = src[1];
        *(bf16x8*)&Ws[row * 256 + ((g ^ (row & 7)) * 8)] = cvt8(f0, f1);
    }
    __syncthreads();

    f32x4 acc[2];
    acc[0] = (f32x4){0.f, 0.f, 0.f, 0.f};
    acc[1] = (f32x4){0.f, 0.f, 0.f, 0.f};

    const int vrow = wc * 16 + ln;
    const ushort* abase = catp_pk + ((size_t)(wr * 2) * 512 + l) * 8;

#pragma unroll
    for (int t = 0; t < 8; ++t) {
        bf16x8 af[2];
        af[0] = *(const bf16x8*)(abase + ((size_t)0 * 512 + t * 64) * 8);
        af[1] = *(const bf16x8*)(abase + ((size_t)1 * 512 + t * 64) * 8);
        int gB = (t * 4 + q) ^ (vrow & 7);
        bf16x8 bfr = *(const bf16x8*)&Ws[vrow * 256 + gB * 8];
#pragma unroll
        for (int mf = 0; mf < 2; ++mf)
            acc[mf] = __builtin_amdgcn_mfma_f32_16x16x32_bf16(af[mf], bfr, acc[mf], 0, 0, 0);
    }

    const int v = v0 + vrow;
    if (v < VOC) {
        float bias = out_b[v];
#pragma unroll
        for (int mf = 0; mf < 2; ++mf) {
            int b0 = wr * 32 + mf * 16 + q * 4;
#pragma unroll
            for (int r = 0; r < 4; ++r)
                wd[(size_t)(b0 + r) * VOC + v] = acc[mf][r] + bias;
        }
    }
}

extern "C" void kernel_launch(void* const* d_in, const int* in_sizes, int n_in,
                              void* d_out, int out_size, void* d_ws, size_t ws_size,
                              hipStream_t stream) {
    const int*   word   = (const int*)  d_in[0];
    const float* hidden = (const float*)d_in[1];
    const float* cell   = (const float*)d_in[2];
    const float* enc    = (const float*)d_in[3];
    const float* embed  = (const float*)d_in[5];
    const float* W_ih   = (const float*)d_in[6];
    const float* W_hh   = (const float*)d_in[7];
    const float* b_ih   = (const float*)d_in[8];
    const float* b_hh   = (const float*)d_in[9];
    const float* attn_W = (const float*)d_in[10];
    const float* attn_b = (const float*)d_in[11];
    const float* vvec   = (const float*)d_in[12];
    const float* proj_W = (const float*)d_in[13];
    const float* proj_b = (const float*)d_in[14];
    const float* out_W  = (const float*)d_in[15];
    const float* out_b  = (const float*)d_in[16];

    float* wd  = (float*)d_out;
    float* h_o = wd + (size_t)BB * VOC;
    float* c_o = h_o + BB * HID;

    float* ws    = (float*)d_ws;
    float* part  = ws;                          // 786432
    float* hproj = part + 786432;               // 16384
    float* ctxp  = hproj + 16384;               // 229376
    float* mls   = ctxp + 229376;               // 896
    ushort* wenc_pk = (ushort*)(mls + 896);     // 131072 ushorts
    ushort* catp_pk = wenc_pk + 131072;         // 16384 ushorts

    k_gates<<<dim3(16, KSP + 1), 256, 0, stream>>>(word, hidden, embed, W_ih, W_hh, part, attn_W, wenc_pk);
    k_lstm<<<dim3(64, 4), 256, 0, stream>>>(part, cell, b_ih, b_hh, attn_W, attn_b, h_o, c_o, hproj);
    k_attn<<<BB * NCHK, 512, 0, stream>>>(enc, wenc_pk, hproj, vvec, ctxp, mls);
    k_comb<<<64, 256, 0, stream>>>(ctxp, mls, h_o, proj_W, proj_b, catp_pk);
    k_out<<<1563, 256, 0, stream>>>(catp_pk, out_W, out_b, wd);
}